// Round 1
// 293.460 us; speedup vs baseline: 1.1992x; 1.1992x over previous
//
#include <hip/hip_runtime.h>

using u16 = unsigned short;
using u32 = unsigned int;

typedef __bf16 bf16x8 __attribute__((ext_vector_type(8)));
typedef float f32x4 __attribute__((ext_vector_type(4)));

#define GLD_LDS16(gp, lp)                                                                 \
  __builtin_amdgcn_global_load_lds((const __attribute__((address_space(1))) void*)(gp),   \
                                   (__attribute__((address_space(3))) void*)(lp), 16, 0, 0)

__device__ __forceinline__ u16 f2b(float f) {
  union { float f; u32 u; } v; v.f = f;
  return (u16)((v.u + 0x7fffu + ((v.u >> 16) & 1u)) >> 16);
}

// ---------------- transpose+cast four 1024x1024 f32 weights -> bf16 W^T ----------------
__global__ __launch_bounds__(256) void transpose4(
    const float* __restrict__ w0, const float* __restrict__ w1,
    const float* __restrict__ w2, const float* __restrict__ w3,
    u16* __restrict__ o0, u16* __restrict__ o1,
    u16* __restrict__ o2, u16* __restrict__ o3) {
  const float* src; u16* dst;
  switch (blockIdx.z) {
    case 0: src = w0; dst = o0; break;
    case 1: src = w1; dst = o1; break;
    case 2: src = w2; dst = o2; break;
    default: src = w3; dst = o3; break;
  }
  __shared__ float tile[64][65];
  int bx = blockIdx.x * 64, by = blockIdx.y * 64;
  int tx = threadIdx.x & 63, ty = threadIdx.x >> 6;
  for (int r = ty; r < 64; r += 4)
    tile[r][tx] = src[(size_t)(by + r) * 1024 + bx + tx];
  __syncthreads();
  for (int r = ty; r < 64; r += 4)
    dst[(size_t)(bx + r) * 1024 + by + tx] = f2b(tile[tx][r]);
}

// ------- bf16 MFMA GEMM: C[M][1024] = A[M][1024] * W, BT = W^T (bf16) -------
#define BM 128
#define BN 128
#define BK 64

template <bool AF32, bool OUTF32>
__global__ __launch_bounds__(256) void gemm_bt(
    const void* __restrict__ Ap, const u16* __restrict__ BT, void* __restrict__ Cp,
    int M, float scale) {
  __shared__ __align__(16) u16 As[BM * BK];
  __shared__ __align__(16) u16 Bs[BN * BK];
  const int K = 1024, N = 1024;
  int tid = threadIdx.x;
  int wave = tid >> 6, lane = tid & 63;
  int r = lane & 15, kg = lane >> 4;
  int bm = blockIdx.x * BM, bn = blockIdx.y * BN;
  int wr = (wave >> 1) * 64, wc = (wave & 1) * 64;
  f32x4 acc[4][4] = {};

  const u16* Bg = BT + (size_t)(bn + wave * 32 + (lane >> 3)) * K + (lane & 7) * 8;
  u16* Bsb = Bs + wave * 32 * BK;

  const float* Af = (const float*)Ap;
  const u16* Ag = nullptr;
  u16* Asb = As + wave * 32 * BK;
  if constexpr (!AF32)
    Ag = (const u16*)Ap + (size_t)(bm + wave * 32 + (lane >> 3)) * K + (lane & 7) * 8;

  for (int k0 = 0; k0 < K; k0 += BK) {
    if constexpr (AF32) {
#pragma unroll
      for (int c = 0; c < 4; ++c) {
        int arow = c * 32 + (tid >> 3);
        const float* p = Af + (size_t)(bm + arow) * K + k0 + (tid & 7) * 8;
        float4 f0 = *(const float4*)p;
        float4 f1 = *(const float4*)(p + 4);
        bf16x8 v;
        v[0] = (__bf16)f0.x; v[1] = (__bf16)f0.y; v[2] = (__bf16)f0.z; v[3] = (__bf16)f0.w;
        v[4] = (__bf16)f1.x; v[5] = (__bf16)f1.y; v[6] = (__bf16)f1.z; v[7] = (__bf16)f1.w;
        *(bf16x8*)&As[arow * BK + (tid & 7) * 8] = v;
      }
#pragma unroll
      for (int c = 0; c < 4; ++c)
        GLD_LDS16(Bg + (size_t)c * 8 * K + k0, Bsb + c * 8 * BK);
    } else {
#pragma unroll
      for (int c = 0; c < 4; ++c) {
        GLD_LDS16(Ag + (size_t)c * 8 * K + k0, Asb + c * 8 * BK);
        GLD_LDS16(Bg + (size_t)c * 8 * K + k0, Bsb + c * 8 * BK);
      }
    }
    __syncthreads();
#pragma unroll
    for (int kk = 0; kk < 2; ++kk) {
      bf16x8 af[4], bfv[4];
#pragma unroll
      for (int m = 0; m < 4; ++m)
        af[m] = *(const bf16x8*)&As[(wr + m * 16 + r) * BK + kk * 32 + kg * 8];
#pragma unroll
      for (int n = 0; n < 4; ++n)
        bfv[n] = *(const bf16x8*)&Bs[(wc + n * 16 + r) * BK + kk * 32 + kg * 8];
#pragma unroll
      for (int m = 0; m < 4; ++m)
#pragma unroll
        for (int n = 0; n < 4; ++n)
          acc[m][n] = __builtin_amdgcn_mfma_f32_16x16x32_bf16(af[m], bfv[n], acc[m][n], 0, 0, 0);
    }
    __syncthreads();
  }

#pragma unroll
  for (int m = 0; m < 4; ++m)
#pragma unroll
    for (int n = 0; n < 4; ++n)
#pragma unroll
      for (int i = 0; i < 4; ++i) {
        int row = bm + wr + m * 16 + kg * 4 + i;
        int col = bn + wc + n * 16 + r;
        if constexpr (OUTF32)
          ((float*)Cp)[(size_t)row * N + col] = acc[m][n][i] * scale;
        else
          ((u16*)Cp)[(size_t)row * N + col] = f2b(acc[m][n][i] * scale);
      }
}

// ---------------- flash attention: per (qtile, head, batch) ----------------
// KVBLK=64; all LDS tiles are [row][128B] with 16B-chunk XOR swizzle
// (chunk' = chunk ^ (row&7)) so every ds_read_b128 is bank-conflict-free.
// K staged via global_load_lds with pre-swizzled SOURCE (linear LDS dest).
__global__ __launch_bounds__(256) void flash_attn(
    const u16* __restrict__ Q, const u16* __restrict__ Km, const u16* __restrict__ Vm,
    const float* __restrict__ bias, u16* __restrict__ ctx) {
  const int S = 2048, H = 1024;
  __shared__ __align__(16) u16 Ks[64 * 64];      // [key][d]   (swizzled)
  __shared__ __align__(16) u16 Vt[64 * 64];      // [d][kv]    (swizzled)
  __shared__ __align__(16) u16 Ps[4][16 * 64];   // [wave][q][key] (swizzled)
  __shared__ float biasS[2048];
  int tid = threadIdx.x;
  int wave = tid >> 6, lane = tid & 63;
  int r = lane & 15, kg = lane >> 4;
  int qt = blockIdx.x, h = blockIdx.y, b = blockIdx.z;

  for (int i = tid; i < S; i += 256) biasS[i] = bias[b * S + i];

  const u16* Qb = Q + (size_t)(b * S + qt * 64 + wave * 16 + r) * H + h * 64 + kg * 8;
  bf16x8 qa[2];
  qa[0] = *(const bf16x8*)(Qb);
  qa[1] = *(const bf16x8*)(Qb + 32);

  // K staging: wave w owns key rows [w*16, w*16+16), 2 loads of 8 rows.
  // LDS dest linear; source chunk pre-swizzled: ch = (lane&7) ^ ((lane>>3)&7)
  int ksrow = lane >> 3;
  int ksch = (lane & 7) ^ (ksrow & 7);
  const u16* KgB = Km + (size_t)b * S * H + h * 64;
  const u16* VgB = Vm + (size_t)b * S * H + h * 64;
  u16* KsW = Ks + wave * 16 * 64;

  float m_i[4], l_i[4];
  f32x4 acc[4] = {};
#pragma unroll
  for (int i = 0; i < 4; ++i) { m_i[i] = -1e30f; l_i[i] = 0.f; }

  u16* Pw = &Ps[wave][0];

  for (int kv0 = 0; kv0 < S; kv0 += 64) {
    // --- stage K [64 keys][64 d] via global_load_lds (swizzled source) ---
#pragma unroll
    for (int c = 0; c < 2; ++c)
      GLD_LDS16(KgB + (size_t)(kv0 + wave * 16 + c * 8 + ksrow) * H + ksch * 8,
                KsW + c * 8 * 64);
    // --- stage V transposed: lane = kv row, wave picks d-octet; writes span
    // full 128B rows via swizzle -> conflict-free ---
#pragma unroll
    for (int c = 0; c < 2; ++c) {
      int d0 = (c * 4 + wave) * 8;
      const u16* vg = VgB + (size_t)(kv0 + lane) * H + d0;
      ushort4 x0 = *(const ushort4*)(vg);
      ushort4 x1 = *(const ushort4*)(vg + 4);
      u16 vv[8] = {(u16)x0.x, (u16)x0.y, (u16)x0.z, (u16)x0.w,
                   (u16)x1.x, (u16)x1.y, (u16)x1.z, (u16)x1.w};
#pragma unroll
      for (int j = 0; j < 8; ++j) {
        int d = d0 + j;
        Vt[d * 64 + ((((lane >> 3) ^ (d & 7)) << 3) | (lane & 7))] = vv[j];
      }
    }
    __syncthreads();

    // --- QK^T: 16 q-rows x 64 keys per wave (8 MFMA) ---
    f32x4 sv[4] = {};
    __builtin_amdgcn_s_setprio(1);
#pragma unroll
    for (int kk = 0; kk < 2; ++kk) {
#pragma unroll
      for (int n = 0; n < 4; ++n) {
        bf16x8 kb = *(const bf16x8*)&Ks[(n * 16 + r) * 64 +
                                        ((((kk << 2) + kg) ^ (r & 7)) << 3)];
        sv[n] = __builtin_amdgcn_mfma_f32_16x16x32_bf16(qa[kk], kb, sv[n], 0, 0, 0);
      }
    }
    __builtin_amdgcn_s_setprio(0);

    // --- online softmax (defer-max, THR=8) ---
    const float* bp = biasS + kv0;
#pragma unroll
    for (int i = 0; i < 4; ++i) {
      float s0 = sv[0][i] + bp[r];
      float s1 = sv[1][i] + bp[16 + r];
      float s2 = sv[2][i] + bp[32 + r];
      float s3 = sv[3][i] + bp[48 + r];
      float mx = fmaxf(fmaxf(s0, s1), fmaxf(s2, s3));
#pragma unroll
      for (int d = 1; d < 16; d <<= 1) mx = fmaxf(mx, __shfl_xor(mx, d));
      if (mx > m_i[i] + 8.f) {  // rescale only when max actually grows
        float sc = __expf(m_i[i] - mx);
        l_i[i] *= sc;
#pragma unroll
        for (int n = 0; n < 4; ++n) acc[n][i] *= sc;
        m_i[i] = mx;
      }
      float e0 = __expf(s0 - m_i[i]);
      float e1 = __expf(s1 - m_i[i]);
      float e2 = __expf(s2 - m_i[i]);
      float e3 = __expf(s3 - m_i[i]);
      float rs = (e0 + e1) + (e2 + e3);
#pragma unroll
      for (int d = 1; d < 16; d <<= 1) rs += __shfl_xor(rs, d);
      l_i[i] += rs;
      int row = (kg << 2) + i;
      int sw = row & 7, lo = r & 7, hi = r >> 3;
      Pw[row * 64 + ((((hi) ^ sw) << 3) | lo)] = f2b(e0);
      Pw[row * 64 + ((((2 + hi) ^ sw) << 3) | lo)] = f2b(e1);
      Pw[row * 64 + ((((4 + hi) ^ sw) << 3) | lo)] = f2b(e2);
      Pw[row * 64 + ((((6 + hi) ^ sw) << 3) | lo)] = f2b(e3);
    }

    // --- PV: ctx[16][64] += P[16][64] * V[64][64] (8 MFMA) ---
    __builtin_amdgcn_s_setprio(1);
#pragma unroll
    for (int kk = 0; kk < 2; ++kk) {
      bf16x8 pa = *(const bf16x8*)&Pw[r * 64 + ((((kk << 2) + kg) ^ (r & 7)) << 3)];
#pragma unroll
      for (int n = 0; n < 4; ++n) {
        bf16x8 vb = *(const bf16x8*)&Vt[(n * 16 + r) * 64 +
                                        ((((kk << 2) + kg) ^ (r & 7)) << 3)];
        acc[n] = __builtin_amdgcn_mfma_f32_16x16x32_bf16(pa, vb, acc[n], 0, 0, 0);
      }
    }
    __builtin_amdgcn_s_setprio(0);
    __syncthreads();
  }

#pragma unroll
  for (int i = 0; i < 4; ++i) {
    float inv = 1.0f / l_i[i];
    size_t row = (size_t)(b * S + qt * 64 + wave * 16 + kg * 4 + i);
#pragma unroll
    for (int n = 0; n < 4; ++n)
      ctx[row * H + h * 64 + n * 16 + r] = f2b(acc[n][i] * inv);
  }
}

extern "C" void kernel_launch(void* const* d_in, const int* in_sizes, int n_in,
                              void* d_out, int out_size, void* d_ws, size_t ws_size,
                              hipStream_t stream) {
  const float* x    = (const float*)d_in[0];
  const float* y    = (const float*)d_in[1];
  const float* bias = (const float*)d_in[2];
  const float* wq   = (const float*)d_in[3];
  const float* wk   = (const float*)d_in[4];
  const float* wv   = (const float*)d_in[5];
  const float* wo   = (const float*)d_in[6];
  float* out = (float*)d_out;  // reference output dtype is float32

  u16* ws = (u16*)d_ws;
  const size_t WELEM = 1024 * 1024;          // 2MB each (bf16)
  const size_t MELEM = (size_t)4096 * 1024;  // 8MB each (bf16)
  u16* wqT = ws;
  u16* wkT = wqT + WELEM;
  u16* wvT = wkT + WELEM;
  u16* woT = wvT + WELEM;
  u16* Qb  = woT + WELEM;
  u16* Kb  = Qb + MELEM;
  u16* Vb  = Kb + MELEM;
  u16* Cb  = Qb;  // reuse: each flash block reads exactly the Q region it writes

  dim3 blk(256);
  transpose4<<<dim3(16, 16, 4), blk, 0, stream>>>(wq, wk, wv, wo, wqT, wkT, wvT, woT);
  gemm_bt<true, false><<<dim3(32, 8), blk, 0, stream>>>(x, wqT, Qb, 4096, 0.125f);
  gemm_bt<true, false><<<dim3(32, 8), blk, 0, stream>>>(y, wkT, Kb, 4096, 1.0f);
  gemm_bt<true, false><<<dim3(32, 8), blk, 0, stream>>>(y, wvT, Vb, 4096, 1.0f);
  flash_attn<<<dim3(32, 16, 2), blk, 0, stream>>>(Qb, Kb, Vb, bias, Cb);
  gemm_bt<false, true><<<dim3(32, 8), blk, 0, stream>>>(Cb, woT, out, 4096, 1.0f);
}

// Round 2
// 269.906 us; speedup vs baseline: 1.3038x; 1.0873x over previous
//
#include <hip/hip_runtime.h>

using u16 = unsigned short;
using u32 = unsigned int;

typedef __bf16 bf16x8 __attribute__((ext_vector_type(8)));
typedef float f32x4 __attribute__((ext_vector_type(4)));
typedef u16 u16x8 __attribute__((ext_vector_type(8)));

#define GLD_LDS16(gp, lp)                                                                 \
  __builtin_amdgcn_global_load_lds((const __attribute__((address_space(1))) void*)(gp),   \
                                   (__attribute__((address_space(3))) void*)(lp), 16, 0, 0)

__device__ __forceinline__ u16 f2b(float f) {
  union { float f; u32 u; } v; v.f = f;
  return (u16)((v.u + 0x7fffu + ((v.u >> 16) & 1u)) >> 16);
}

// ---------------- transpose+cast four 1024x1024 f32 weights -> bf16 W^T ----------------
__global__ __launch_bounds__(256) void transpose4(
    const float* __restrict__ w0, const float* __restrict__ w1,
    const float* __restrict__ w2, const float* __restrict__ w3,
    u16* __restrict__ o0, u16* __restrict__ o1,
    u16* __restrict__ o2, u16* __restrict__ o3) {
  const float* src; u16* dst;
  switch (blockIdx.z) {
    case 0: src = w0; dst = o0; break;
    case 1: src = w1; dst = o1; break;
    case 2: src = w2; dst = o2; break;
    default: src = w3; dst = o3; break;
  }
  __shared__ float tile[64][65];
  int bx = blockIdx.x * 64, by = blockIdx.y * 64;
  int tx = threadIdx.x & 63, ty = threadIdx.x >> 6;
  for (int r = ty; r < 64; r += 4)
    tile[r][tx] = src[(size_t)(by + r) * 1024 + bx + tx];
  __syncthreads();
  for (int r = ty; r < 64; r += 4)
    dst[(size_t)(bx + r) * 1024 + by + tx] = f2b(tile[tx][r]);
}

// ------- bf16 MFMA GEMM: C[M][1024] = A[M][1024] * W, BT = W^T (bf16) -------
#define BM 128
#define BN 128
#define BK 64

template <bool AF32, bool OUTF32>
__global__ __launch_bounds__(256) void gemm_bt(
    const void* __restrict__ Ap, const u16* __restrict__ BT, void* __restrict__ Cp,
    int M, float scale) {
  __shared__ __align__(16) u16 As[BM * BK];
  __shared__ __align__(16) u16 Bs[BN * BK];
  const int K = 1024, N = 1024;
  int tid = threadIdx.x;
  int wave = tid >> 6, lane = tid & 63;
  int r = lane & 15, kg = lane >> 4;
  int bm = blockIdx.x * BM, bn = blockIdx.y * BN;
  int wr = (wave >> 1) * 64, wc = (wave & 1) * 64;
  f32x4 acc[4][4] = {};

  const u16* Bg = BT + (size_t)(bn + wave * 32 + (lane >> 3)) * K + (lane & 7) * 8;
  u16* Bsb = Bs + wave * 32 * BK;

  const float* Af = (const float*)Ap;
  const u16* Ag = nullptr;
  u16* Asb = As + wave * 32 * BK;
  if constexpr (!AF32)
    Ag = (const u16*)Ap + (size_t)(bm + wave * 32 + (lane >> 3)) * K + (lane & 7) * 8;

  for (int k0 = 0; k0 < K; k0 += BK) {
    if constexpr (AF32) {
#pragma unroll
      for (int c = 0; c < 4; ++c) {
        int arow = c * 32 + (tid >> 3);
        const float* p = Af + (size_t)(bm + arow) * K + k0 + (tid & 7) * 8;
        float4 f0 = *(const float4*)p;
        float4 f1 = *(const float4*)(p + 4);
        bf16x8 v;
        v[0] = (__bf16)f0.x; v[1] = (__bf16)f0.y; v[2] = (__bf16)f0.z; v[3] = (__bf16)f0.w;
        v[4] = (__bf16)f1.x; v[5] = (__bf16)f1.y; v[6] = (__bf16)f1.z; v[7] = (__bf16)f1.w;
        *(bf16x8*)&As[arow * BK + (tid & 7) * 8] = v;
      }
#pragma unroll
      for (int c = 0; c < 4; ++c)
        GLD_LDS16(Bg + (size_t)c * 8 * K + k0, Bsb + c * 8 * BK);
    } else {
#pragma unroll
      for (int c = 0; c < 4; ++c) {
        GLD_LDS16(Ag + (size_t)c * 8 * K + k0, Asb + c * 8 * BK);
        GLD_LDS16(Bg + (size_t)c * 8 * K + k0, Bsb + c * 8 * BK);
      }
    }
    __syncthreads();
#pragma unroll
    for (int kk = 0; kk < 2; ++kk) {
      bf16x8 af[4], bfv[4];
#pragma unroll
      for (int m = 0; m < 4; ++m)
        af[m] = *(const bf16x8*)&As[(wr + m * 16 + r) * BK + kk * 32 + kg * 8];
#pragma unroll
      for (int n = 0; n < 4; ++n)
        bfv[n] = *(const bf16x8*)&Bs[(wc + n * 16 + r) * BK + kk * 32 + kg * 8];
#pragma unroll
      for (int m = 0; m < 4; ++m)
#pragma unroll
        for (int n = 0; n < 4; ++n)
          acc[m][n] = __builtin_amdgcn_mfma_f32_16x16x32_bf16(af[m], bfv[n], acc[m][n], 0, 0, 0);
    }
    __syncthreads();
  }

#pragma unroll
  for (int m = 0; m < 4; ++m)
#pragma unroll
    for (int n = 0; n < 4; ++n)
#pragma unroll
      for (int i = 0; i < 4; ++i) {
        int row = bm + wr + m * 16 + kg * 4 + i;
        int col = bn + wc + n * 16 + r;
        if constexpr (OUTF32)
          ((float*)Cp)[(size_t)row * N + col] = acc[m][n][i] * scale;
        else
          ((u16*)Cp)[(size_t)row * N + col] = f2b(acc[m][n][i] * scale);
      }
}

// ---------------- flash attention: per (head, batch, qtile) ----------------
// Grid ordered (h,b) in the low bits so all 32 q-tiles of one (h,b) land on
// one XCD (id%8 = h%8): K/V (512 KB) becomes L2-resident per XCD.
// Double-buffered KV pipeline: tile t+1's K (global_load_lds), V (reg) and
// bias (reg) are issued BEFORE computing tile t; latency hides under compute.
// One barrier per tile. All LDS tiles 16B-chunk XOR-swizzled (conflict-free).
__global__ __launch_bounds__(256) void flash_attn(
    const u16* __restrict__ Q, const u16* __restrict__ Km, const u16* __restrict__ Vm,
    const float* __restrict__ bias, u16* __restrict__ ctx) {
  const int S = 2048, H = 1024;
  __shared__ __align__(16) u16 Ks[2][64 * 64];   // [buf][key][d]  (swizzled)
  __shared__ __align__(16) u16 Vt[2][64 * 64];   // [buf][d][kv]   (swizzled)
  __shared__ __align__(16) u16 Ps[4][16 * 64];   // [wave][q][key] (swizzled)
  int tid = threadIdx.x;
  int wave = tid >> 6, lane = tid & 63;
  int r = lane & 15, kg = lane >> 4;
  int h = blockIdx.x, b = blockIdx.y, qt = blockIdx.z;

  const u16* Qb = Q + (size_t)(b * S + qt * 64 + wave * 16 + r) * H + h * 64 + kg * 8;
  bf16x8 qa[2];
  qa[0] = *(const bf16x8*)(Qb);
  qa[1] = *(const bf16x8*)(Qb + 32);

  int lhi = lane >> 3, llo = lane & 7;
  int ksch = llo ^ lhi;  // pre-swizzled source chunk for K staging
  const u16* KgB = Km + (size_t)b * S * H + h * 64;
  const u16* VgB = Vm + (size_t)b * S * H + h * 64;
  const float* biasB = bias + (size_t)b * S;

  float m_i[4], l_i[4];
  f32x4 acc[4] = {};
#pragma unroll
  for (int i = 0; i < 4; ++i) { m_i[i] = -1e30f; l_i[i] = 0.f; }

  u16* Pw = &Ps[wave][0];

  auto issueK = [&](int kv0, int bi) {
#pragma unroll
    for (int c = 0; c < 2; ++c)
      GLD_LDS16(KgB + (size_t)(kv0 + wave * 16 + c * 8 + lhi) * H + ksch * 8,
                &Ks[bi][wave * 16 * 64 + c * 8 * 64]);
  };
  auto issueV = [&](int kv0, u16x8* vr) {
#pragma unroll
    for (int c = 0; c < 2; ++c)
      vr[c] = *(const u16x8*)(VgB + (size_t)(kv0 + lane) * H + (c * 4 + wave) * 8);
  };
  auto issueB = [&](int kv0, float* bb) {
#pragma unroll
    for (int n = 0; n < 4; ++n) bb[n] = biasB[kv0 + n * 16 + r];
  };
  auto writeV = [&](const u16x8* vr, int bi) {
#pragma unroll
    for (int c = 0; c < 2; ++c) {
      int d0 = (c * 4 + wave) * 8;
#pragma unroll
      for (int j = 0; j < 8; ++j)
        Vt[bi][(d0 + j) * 64 + (((lhi ^ j) << 3) | llo)] = vr[c][j];
    }
  };
  auto compute = [&](const u16* KsB, const u16* VtB, const float* bb) {
    // QK^T: 16 q-rows x 64 keys (8 MFMA)
    f32x4 sv[4] = {};
    __builtin_amdgcn_s_setprio(1);
#pragma unroll
    for (int kk = 0; kk < 2; ++kk)
#pragma unroll
      for (int n = 0; n < 4; ++n) {
        bf16x8 kb = *(const bf16x8*)&KsB[(n * 16 + r) * 64 +
                                         ((((kk << 2) + kg) ^ (r & 7)) << 3)];
        sv[n] = __builtin_amdgcn_mfma_f32_16x16x32_bf16(qa[kk], kb, sv[n], 0, 0, 0);
      }
    __builtin_amdgcn_s_setprio(0);
    // online softmax (defer-max, THR=8)
#pragma unroll
    for (int i = 0; i < 4; ++i) {
      float s0 = sv[0][i] + bb[0];
      float s1 = sv[1][i] + bb[1];
      float s2 = sv[2][i] + bb[2];
      float s3 = sv[3][i] + bb[3];
      float mx = fmaxf(fmaxf(s0, s1), fmaxf(s2, s3));
#pragma unroll
      for (int d = 1; d < 16; d <<= 1) mx = fmaxf(mx, __shfl_xor(mx, d));
      if (mx > m_i[i] + 8.f) {
        float sc = __expf(m_i[i] - mx);
        l_i[i] *= sc;
#pragma unroll
        for (int n = 0; n < 4; ++n) acc[n][i] *= sc;
        m_i[i] = mx;
      }
      float e0 = __expf(s0 - m_i[i]);
      float e1 = __expf(s1 - m_i[i]);
      float e2 = __expf(s2 - m_i[i]);
      float e3 = __expf(s3 - m_i[i]);
      float rs = (e0 + e1) + (e2 + e3);
#pragma unroll
      for (int d = 1; d < 16; d <<= 1) rs += __shfl_xor(rs, d);
      l_i[i] += rs;
      int row = (kg << 2) + i;
      int sw = row & 7, lo = r & 7, hi = r >> 3;
      Pw[row * 64 + (((hi ^ sw) << 3) | lo)] = f2b(e0);
      Pw[row * 64 + ((((2 + hi) ^ sw) << 3) | lo)] = f2b(e1);
      Pw[row * 64 + ((((4 + hi) ^ sw) << 3) | lo)] = f2b(e2);
      Pw[row * 64 + ((((6 + hi) ^ sw) << 3) | lo)] = f2b(e3);
    }
    // PV: ctx[16][64] += P[16][64] * V[64][64] (8 MFMA)
    __builtin_amdgcn_s_setprio(1);
#pragma unroll
    for (int kk = 0; kk < 2; ++kk) {
      bf16x8 pa = *(const bf16x8*)&Pw[r * 64 + ((((kk << 2) + kg) ^ (r & 7)) << 3)];
#pragma unroll
      for (int n = 0; n < 4; ++n) {
        bf16x8 vb = *(const bf16x8*)&VtB[(n * 16 + r) * 64 +
                                         ((((kk << 2) + kg) ^ (r & 7)) << 3)];
        acc[n] = __builtin_amdgcn_mfma_f32_16x16x32_bf16(pa, vb, acc[n], 0, 0, 0);
      }
    }
    __builtin_amdgcn_s_setprio(0);
  };

  u16x8 vp[2], vn[2];
  float bp[4], bn[4];

  // prologue: tile 0 into buf 0
  issueK(0, 0); issueV(0, vp); issueB(0, bp);
  writeV(vp, 0);
  __syncthreads();

  for (int t2 = 0; t2 < 16; ++t2) {
    int kv1 = (t2 * 2 + 1) * 64;
    int kv2 = ((t2 * 2 + 2) & 31) * 64;  // wraps at end (harmless refetch)
    // tile 2*t2 (buf 0); prefetch tile 2*t2+1 into buf 1
    issueK(kv1, 1); issueV(kv1, vn); issueB(kv1, bn);
    compute(Ks[0], Vt[0], bp);
    writeV(vn, 1);
    __syncthreads();
    // tile 2*t2+1 (buf 1); prefetch tile 2*t2+2 into buf 0
    issueK(kv2, 0); issueV(kv2, vp); issueB(kv2, bp);
    compute(Ks[1], Vt[1], bn);
    writeV(vp, 0);
    __syncthreads();
  }

#pragma unroll
  for (int i = 0; i < 4; ++i) {
    float inv = 1.0f / l_i[i];
    size_t row = (size_t)(b * S + qt * 64 + wave * 16 + kg * 4 + i);
#pragma unroll
    for (int n = 0; n < 4; ++n)
      ctx[row * H + h * 64 + n * 16 + r] = f2b(acc[n][i] * inv);
  }
}

extern "C" void kernel_launch(void* const* d_in, const int* in_sizes, int n_in,
                              void* d_out, int out_size, void* d_ws, size_t ws_size,
                              hipStream_t stream) {
  const float* x    = (const float*)d_in[0];
  const float* y    = (const float*)d_in[1];
  const float* bias = (const float*)d_in[2];
  const float* wq   = (const float*)d_in[3];
  const float* wk   = (const float*)d_in[4];
  const float* wv   = (const float*)d_in[5];
  const float* wo   = (const float*)d_in[6];
  float* out = (float*)d_out;  // reference output dtype is float32

  u16* ws = (u16*)d_ws;
  const size_t WELEM = 1024 * 1024;          // 2MB each (bf16)
  const size_t MELEM = (size_t)4096 * 1024;  // 8MB each (bf16)
  u16* wqT = ws;
  u16* wkT = wqT + WELEM;
  u16* wvT = wkT + WELEM;
  u16* woT = wvT + WELEM;
  u16* Qb  = woT + WELEM;
  u16* Kb  = Qb + MELEM;
  u16* Vb  = Kb + MELEM;
  u16* Cb  = Qb;  // reuse: each flash block reads exactly the Q region it writes

  dim3 blk(256);
  transpose4<<<dim3(16, 16, 4), blk, 0, stream>>>(wq, wk, wv, wo, wqT, wkT, wvT, woT);
  gemm_bt<true, false><<<dim3(32, 8), blk, 0, stream>>>(x, wqT, Qb, 4096, 0.125f);
  gemm_bt<true, false><<<dim3(32, 8), blk, 0, stream>>>(y, wkT, Kb, 4096, 1.0f);
  gemm_bt<true, false><<<dim3(32, 8), blk, 0, stream>>>(y, wvT, Vb, 4096, 1.0f);
  // (h,b) fastest -> same-(h,b) q-tiles share an XCD's L2
  flash_attn<<<dim3(16, 2, 32), blk, 0, stream>>>(Qb, Kb, Vb, bias, Cb);
  gemm_bt<false, true><<<dim3(32, 8), blk, 0, stream>>>(Cb, woT, out, 4096, 1.0f);
}

// Round 3
// 201.544 us; speedup vs baseline: 1.7461x; 1.3392x over previous
//
#include <hip/hip_runtime.h>

using u16 = unsigned short;
using u32 = unsigned int;

typedef __bf16 bf16x8 __attribute__((ext_vector_type(8)));
typedef __bf16 bf16x4 __attribute__((ext_vector_type(4)));
typedef float f32x4 __attribute__((ext_vector_type(4)));
typedef u16 u16x4 __attribute__((ext_vector_type(4)));

#define GLD_LDS16(gp, lp)                                                                 \
  __builtin_amdgcn_global_load_lds((const __attribute__((address_space(1))) void*)(gp),   \
                                   (__attribute__((address_space(3))) void*)(lp), 16, 0, 0)

__device__ __forceinline__ u16 f2b(float f) {
  union { float f; u32 u; } v; v.f = f;
  return (u16)((v.u + 0x7fffu + ((v.u >> 16) & 1u)) >> 16);
}

// ---------------- transpose+cast four 1024x1024 f32 weights -> bf16 W^T ----------------
__global__ __launch_bounds__(256) void transpose4(
    const float* __restrict__ w0, const float* __restrict__ w1,
    const float* __restrict__ w2, const float* __restrict__ w3,
    u16* __restrict__ o0, u16* __restrict__ o1,
    u16* __restrict__ o2, u16* __restrict__ o3) {
  const float* src; u16* dst;
  switch (blockIdx.z) {
    case 0: src = w0; dst = o0; break;
    case 1: src = w1; dst = o1; break;
    case 2: src = w2; dst = o2; break;
    default: src = w3; dst = o3; break;
  }
  __shared__ float tile[64][65];
  int bx = blockIdx.x * 64, by = blockIdx.y * 64;
  int tx = threadIdx.x & 63, ty = threadIdx.x >> 6;
  for (int r = ty; r < 64; r += 4)
    tile[r][tx] = src[(size_t)(by + r) * 1024 + bx + tx];
  __syncthreads();
  for (int r = ty; r < 64; r += 4)
    dst[(size_t)(bx + r) * 1024 + by + tx] = f2b(tile[tx][r]);
}

// ------- bf16 MFMA GEMM: C[M][1024] = A[M][1024] * W, BT = W^T (bf16) -------
// OMODE: 0 = bf16 row-major, 1 = f32 row-major, 2 = bf16 V^T per-head
//        ([b][h][d][s] with b=row>>11, s=row&2047, h=col>>6, d=col&63)
#define BM 128
#define BN 128
#define BK 64

template <bool AF32, int OMODE>
__global__ __launch_bounds__(256) void gemm_bt(
    const void* __restrict__ Ap, const u16* __restrict__ BT, void* __restrict__ Cp,
    int M, float scale) {
  __shared__ __align__(16) u16 As[BM * BK];
  __shared__ __align__(16) u16 Bs[BN * BK];
  const int K = 1024, N = 1024;
  int tid = threadIdx.x;
  int wave = tid >> 6, lane = tid & 63;
  int r = lane & 15, kg = lane >> 4;
  int bm = blockIdx.x * BM, bn = blockIdx.y * BN;
  int wr = (wave >> 1) * 64, wc = (wave & 1) * 64;
  f32x4 acc[4][4] = {};

  const u16* Bg = BT + (size_t)(bn + wave * 32 + (lane >> 3)) * K + (lane & 7) * 8;
  u16* Bsb = Bs + wave * 32 * BK;

  const float* Af = (const float*)Ap;
  const u16* Ag = nullptr;
  u16* Asb = As + wave * 32 * BK;
  if constexpr (!AF32)
    Ag = (const u16*)Ap + (size_t)(bm + wave * 32 + (lane >> 3)) * K + (lane & 7) * 8;

  for (int k0 = 0; k0 < K; k0 += BK) {
    if constexpr (AF32) {
#pragma unroll
      for (int c = 0; c < 4; ++c) {
        int arow = c * 32 + (tid >> 3);
        const float* p = Af + (size_t)(bm + arow) * K + k0 + (tid & 7) * 8;
        float4 f0 = *(const float4*)p;
        float4 f1 = *(const float4*)(p + 4);
        bf16x8 v;
        v[0] = (__bf16)f0.x; v[1] = (__bf16)f0.y; v[2] = (__bf16)f0.z; v[3] = (__bf16)f0.w;
        v[4] = (__bf16)f1.x; v[5] = (__bf16)f1.y; v[6] = (__bf16)f1.z; v[7] = (__bf16)f1.w;
        *(bf16x8*)&As[arow * BK + (tid & 7) * 8] = v;
      }
#pragma unroll
      for (int c = 0; c < 4; ++c)
        GLD_LDS16(Bg + (size_t)c * 8 * K + k0, Bsb + c * 8 * BK);
    } else {
#pragma unroll
      for (int c = 0; c < 4; ++c) {
        GLD_LDS16(Ag + (size_t)c * 8 * K + k0, Asb + c * 8 * BK);
        GLD_LDS16(Bg + (size_t)c * 8 * K + k0, Bsb + c * 8 * BK);
      }
    }
    __syncthreads();
#pragma unroll
    for (int kk = 0; kk < 2; ++kk) {
      bf16x8 af[4], bfv[4];
#pragma unroll
      for (int m = 0; m < 4; ++m)
        af[m] = *(const bf16x8*)&As[(wr + m * 16 + r) * BK + kk * 32 + kg * 8];
#pragma unroll
      for (int n = 0; n < 4; ++n)
        bfv[n] = *(const bf16x8*)&Bs[(wc + n * 16 + r) * BK + kk * 32 + kg * 8];
#pragma unroll
      for (int m = 0; m < 4; ++m)
#pragma unroll
        for (int n = 0; n < 4; ++n)
          acc[m][n] = __builtin_amdgcn_mfma_f32_16x16x32_bf16(af[m], bfv[n], acc[m][n], 0, 0, 0);
    }
    __syncthreads();
  }

#pragma unroll
  for (int m = 0; m < 4; ++m)
#pragma unroll
    for (int n = 0; n < 4; ++n) {
      if constexpr (OMODE == 2) {
        int row0 = bm + wr + m * 16 + kg * 4;
        int col = bn + wc + n * 16 + r;
        int bb = row0 >> 11, s = row0 & 2047;
        int hh = col >> 6, dd = col & 63;
        u16x4 pk;
#pragma unroll
        for (int i = 0; i < 4; ++i) pk[i] = f2b(acc[m][n][i] * scale);
        *(u16x4*)&((u16*)Cp)[((size_t)(bb * 16 + hh) * 64 + dd) * 2048 + s] = pk;
      } else {
#pragma unroll
        for (int i = 0; i < 4; ++i) {
          int row = bm + wr + m * 16 + kg * 4 + i;
          int col = bn + wc + n * 16 + r;
          if constexpr (OMODE == 1)
            ((float*)Cp)[(size_t)row * N + col] = acc[m][n][i] * scale;
          else
            ((u16*)Cp)[(size_t)row * N + col] = f2b(acc[m][n][i] * scale);
        }
      }
    }
}

// ---------------- flash attention: per (head, batch, qtile) ----------------
// Swapped QK^T: sv = mfma(K_frag, Q_frag) -> lane holds 16 scores of ONE
// q-row (q = r): softmax reduce = in-lane tree + shfl_xor(16,32). m/l scalar.
// V pre-transposed in global ([b][h][d][s]) so BOTH K and V stage via
// global_load_lds (no LDS scatter). All tiles 16B-chunk XOR-swizzled.
__global__ __launch_bounds__(256) void flash_attn(
    const u16* __restrict__ Q, const u16* __restrict__ Km, const u16* __restrict__ VtG,
    const float* __restrict__ bias, u16* __restrict__ ctx) {
  const int S = 2048, H = 1024;
  __shared__ __align__(16) u16 Ks[2][64 * 64];   // [buf][key][d] (swizzled)
  __shared__ __align__(16) u16 Vs[2][64 * 64];   // [buf][d][kv]  (swizzled)
  __shared__ __align__(16) u16 Ps[4][16 * 64];   // [wave][q][key](swizzled)
  int tid = threadIdx.x;
  int wave = tid >> 6, lane = tid & 63;
  int r = lane & 15, kg = lane >> 4;
  int h = blockIdx.x, b = blockIdx.y, qt = blockIdx.z;

  const u16* Qb = Q + (size_t)(b * S + qt * 64 + wave * 16 + r) * H + h * 64 + kg * 8;
  bf16x8 qa[2];
  qa[0] = *(const bf16x8*)(Qb);
  qa[1] = *(const bf16x8*)(Qb + 32);

  int lhi = lane >> 3, llo = lane & 7;
  int ksch = llo ^ lhi;  // pre-swizzled source chunk for DMA staging
  const u16* KgB = Km + (size_t)b * S * H + h * 64;
  const u16* VgB = VtG + ((size_t)(b * 16 + h) * 64) * 2048;  // rows d, stride S
  const float* biasB = bias + (size_t)b * S;

  float m_i = -1e30f, l_i = 0.f;
  f32x4 acc[4] = {};

  u16* Pw = &Ps[wave][0];

  auto issueKV = [&](int kv0, int bi) {
#pragma unroll
    for (int c = 0; c < 2; ++c) {
      GLD_LDS16(KgB + (size_t)(kv0 + wave * 16 + c * 8 + lhi) * H + ksch * 8,
                &Ks[bi][wave * 16 * 64 + c * 8 * 64]);
      GLD_LDS16(VgB + (size_t)(wave * 16 + c * 8 + lhi) * 2048 + kv0 + ksch * 8,
                &Vs[bi][wave * 16 * 64 + c * 8 * 64]);
    }
  };
  auto issueB = [&](int kv0, f32x4* bv) {
#pragma unroll
    for (int n = 0; n < 4; ++n)
      bv[n] = *(const f32x4*)(biasB + kv0 + n * 16 + (kg << 2));
  };

  auto compute = [&](const u16* KsB, const u16* VsB, const f32x4* bv) {
    // QK^T swapped: sv[n][i] = S^T[key = n*16+kg*4+i][q = r]
    f32x4 sv[4] = {};
    __builtin_amdgcn_s_setprio(1);
#pragma unroll
    for (int kk = 0; kk < 2; ++kk)
#pragma unroll
      for (int n = 0; n < 4; ++n) {
        bf16x8 kb = *(const bf16x8*)&KsB[(n * 16 + r) * 64 +
                                         ((((kk << 2) + kg) ^ (r & 7)) << 3)];
        sv[n] = __builtin_amdgcn_mfma_f32_16x16x32_bf16(kb, qa[kk], sv[n], 0, 0, 0);
      }
    __builtin_amdgcn_s_setprio(0);

    f32x4 s4[4];
#pragma unroll
    for (int n = 0; n < 4; ++n) s4[n] = sv[n] + bv[n];
    float m0 = fmaxf(fmaxf(s4[0][0], s4[0][1]), fmaxf(s4[0][2], s4[0][3]));
    float m1 = fmaxf(fmaxf(s4[1][0], s4[1][1]), fmaxf(s4[1][2], s4[1][3]));
    float m2 = fmaxf(fmaxf(s4[2][0], s4[2][1]), fmaxf(s4[2][2], s4[2][3]));
    float m3 = fmaxf(fmaxf(s4[3][0], s4[3][1]), fmaxf(s4[3][2], s4[3][3]));
    float mx = fmaxf(fmaxf(m0, m1), fmaxf(m2, m3));
    mx = fmaxf(mx, __shfl_xor(mx, 16));
    mx = fmaxf(mx, __shfl_xor(mx, 32));
    float sc = 1.f;
    if (mx > m_i + 8.f) { sc = __expf(m_i - mx); l_i *= sc; m_i = mx; }
    if (__any(sc != 1.f)) {
#pragma unroll
      for (int i = 0; i < 4; ++i) {
        float sci = __shfl(sc, (lane & 48) | ((kg << 2) + i));
#pragma unroll
        for (int n = 0; n < 4; ++n) acc[n][i] *= sci;
      }
    }
    float rs = 0.f;
    bf16x4 pk[4];
#pragma unroll
    for (int n = 0; n < 4; ++n)
#pragma unroll
      for (int i = 0; i < 4; ++i) {
        float e = __expf(s4[n][i] - m_i);
        rs += e;
        pk[n][i] = (__bf16)e;
      }
    rs += __shfl_xor(rs, 16);
    rs += __shfl_xor(rs, 32);
    l_i += rs;
    // P[q = r][key]: per n, 4 contiguous u16 at col n*16+kg*4 (swizzled chunk)
#pragma unroll
    for (int n = 0; n < 4; ++n)
      *(bf16x4*)&Pw[r * 64 + ((((2 * n + (kg >> 1)) ^ (r & 7)) << 3) | ((kg & 1) << 2))] =
          pk[n];

    // PV: acc[q = kg*4+i][d = n*16+r] += P[q][k] V^T[d][k]
    __builtin_amdgcn_s_setprio(1);
#pragma unroll
    for (int kk = 0; kk < 2; ++kk) {
      bf16x8 pa = *(const bf16x8*)&Pw[r * 64 + ((((kk << 2) + kg) ^ (r & 7)) << 3)];
#pragma unroll
      for (int n = 0; n < 4; ++n) {
        bf16x8 vb = *(const bf16x8*)&VsB[(n * 16 + r) * 64 +
                                         ((((kk << 2) + kg) ^ (r & 7)) << 3)];
        acc[n] = __builtin_amdgcn_mfma_f32_16x16x32_bf16(pa, vb, acc[n], 0, 0, 0);
      }
    }
    __builtin_amdgcn_s_setprio(0);
  };

  f32x4 bp[4], bn2[4];

  issueKV(0, 0); issueB(0, bp);
  __syncthreads();

  for (int t2 = 0; t2 < 16; ++t2) {
    int kv1 = (t2 * 2 + 1) * 64;
    int kv2 = ((t2 * 2 + 2) & 31) * 64;  // wraps at end (harmless refetch)
    issueKV(kv1, 1); issueB(kv1, bn2);
    compute(Ks[0], Vs[0], bp);
    __syncthreads();
    issueKV(kv2, 0); issueB(kv2, bp);
    compute(Ks[1], Vs[1], bn2);
    __syncthreads();
  }

#pragma unroll
  for (int i = 0; i < 4; ++i) {
    float li = __shfl(l_i, (lane & 48) | ((kg << 2) + i));
    float inv = 1.0f / li;
    size_t row = (size_t)(b * S + qt * 64 + wave * 16 + (kg << 2) + i);
#pragma unroll
    for (int n = 0; n < 4; ++n)
      ctx[row * H + h * 64 + n * 16 + r] = f2b(acc[n][i] * inv);
  }
}

extern "C" void kernel_launch(void* const* d_in, const int* in_sizes, int n_in,
                              void* d_out, int out_size, void* d_ws, size_t ws_size,
                              hipStream_t stream) {
  const float* x    = (const float*)d_in[0];
  const float* y    = (const float*)d_in[1];
  const float* bias = (const float*)d_in[2];
  const float* wq   = (const float*)d_in[3];
  const float* wk   = (const float*)d_in[4];
  const float* wv   = (const float*)d_in[5];
  const float* wo   = (const float*)d_in[6];
  float* out = (float*)d_out;  // reference output dtype is float32

  u16* ws = (u16*)d_ws;
  const size_t WELEM = 1024 * 1024;          // 2MB each (bf16)
  const size_t MELEM = (size_t)4096 * 1024;  // 8MB each (bf16)
  u16* wqT = ws;
  u16* wkT = wqT + WELEM;
  u16* wvT = wkT + WELEM;
  u16* woT = wvT + WELEM;
  u16* Qb  = woT + WELEM;
  u16* Kb  = Qb + MELEM;
  u16* Vb  = Kb + MELEM;   // holds V^T [b][h][d][s]
  u16* Cb  = Qb;  // reuse: each flash block reads exactly the Q region it writes

  dim3 blk(256);
  transpose4<<<dim3(16, 16, 4), blk, 0, stream>>>(wq, wk, wv, wo, wqT, wkT, wvT, woT);
  gemm_bt<true, 0><<<dim3(32, 8), blk, 0, stream>>>(x, wqT, Qb, 4096, 0.125f);
  gemm_bt<true, 0><<<dim3(32, 8), blk, 0, stream>>>(y, wkT, Kb, 4096, 1.0f);
  gemm_bt<true, 2><<<dim3(32, 8), blk, 0, stream>>>(y, wvT, Vb, 4096, 1.0f);
  // (h,b) fastest -> same-(h,b) q-tiles share an XCD's L2
  flash_attn<<<dim3(16, 2, 32), blk, 0, stream>>>(Qb, Kb, Vb, bias, Cb);
  gemm_bt<false, 1><<<dim3(32, 8), blk, 0, stream>>>(Cb, woT, out, 4096, 1.0f);
}

// Round 4
// 189.551 us; speedup vs baseline: 1.8565x; 1.0633x over previous
//
#include <hip/hip_runtime.h>

using u16 = unsigned short;
using u32 = unsigned int;

typedef __bf16 bf16x8 __attribute__((ext_vector_type(8)));
typedef __bf16 bf16x4 __attribute__((ext_vector_type(4)));
typedef float f32x4 __attribute__((ext_vector_type(4)));
typedef u16 u16x4 __attribute__((ext_vector_type(4)));

#define GLD_LDS16(gp, lp)                                                                 \
  __builtin_amdgcn_global_load_lds((const __attribute__((address_space(1))) void*)(gp),   \
                                   (__attribute__((address_space(3))) void*)(lp), 16, 0, 0)

__device__ __forceinline__ u16 f2b(float f) {
  union { float f; u32 u; } v; v.f = f;
  return (u16)((v.u + 0x7fffu + ((v.u >> 16) & 1u)) >> 16);
}

// ---------------- transpose+cast four 1024x1024 f32 weights -> bf16 W^T ----------------
__global__ __launch_bounds__(256) void transpose4(
    const float* __restrict__ w0, const float* __restrict__ w1,
    const float* __restrict__ w2, const float* __restrict__ w3,
    u16* __restrict__ o0, u16* __restrict__ o1,
    u16* __restrict__ o2, u16* __restrict__ o3) {
  const float* src; u16* dst;
  switch (blockIdx.z) {
    case 0: src = w0; dst = o0; break;
    case 1: src = w1; dst = o1; break;
    case 2: src = w2; dst = o2; break;
    default: src = w3; dst = o3; break;
  }
  __shared__ float tile[64][65];
  int bx = blockIdx.x * 64, by = blockIdx.y * 64;
  int tx = threadIdx.x & 63, ty = threadIdx.x >> 6;
  for (int r = ty; r < 64; r += 4)
    tile[r][tx] = src[(size_t)(by + r) * 1024 + bx + tx];
  __syncthreads();
  for (int r = ty; r < 64; r += 4)
    dst[(size_t)(bx + r) * 1024 + by + tx] = f2b(tile[tx][r]);
}

// ---------------- elementwise f32 -> bf16 for x and y (one launch) ----------------
__global__ __launch_bounds__(256) void cvt2bf16(
    const float* __restrict__ a, const float* __restrict__ b,
    u16* __restrict__ oa, u16* __restrict__ ob) {
  const float* src = blockIdx.y ? b : a;
  u16* dst = blockIdx.y ? ob : oa;
  size_t i = ((size_t)blockIdx.x * 256 + threadIdx.x) * 8;
  float4 f0 = *(const float4*)(src + i);
  float4 f1 = *(const float4*)(src + i + 4);
  bf16x8 v;
  v[0] = (__bf16)f0.x; v[1] = (__bf16)f0.y; v[2] = (__bf16)f0.z; v[3] = (__bf16)f0.w;
  v[4] = (__bf16)f1.x; v[5] = (__bf16)f1.y; v[6] = (__bf16)f1.z; v[7] = (__bf16)f1.w;
  *(bf16x8*)(dst + i) = v;
}

// ------- bf16 MFMA GEMM: C[4096][1024] = A[4096][1024] * W, BT = W^T (bf16) -------
// Fully DMA-staged (global_load_lds 16B for both A and B).
// OMODE: 0 = bf16 row-major, 1 = f32 row-major, 2 = bf16 V^T per-head
//        ([b][h][d][s] with b=row>>11, s=row&2047, h=col>>6, d=col&63)
#define BM 128
#define BN 128
#define BK 64

template <int OMODE>
__global__ __launch_bounds__(256) void gemm_bt(
    const u16* __restrict__ A, const u16* __restrict__ BT, void* __restrict__ Cp,
    float scale) {
  __shared__ __align__(16) u16 As[BM * BK];
  __shared__ __align__(16) u16 Bs[BN * BK];
  const int K = 1024, N = 1024;
  int tid = threadIdx.x;
  int wave = tid >> 6, lane = tid & 63;
  int r = lane & 15, kg = lane >> 4;
  int bm = blockIdx.x * BM, bn = blockIdx.y * BN;
  int wr = (wave >> 1) * 64, wc = (wave & 1) * 64;
  f32x4 acc[4][4] = {};

  const u16* Ag = A + (size_t)(bm + wave * 32 + (lane >> 3)) * K + (lane & 7) * 8;
  const u16* Bg = BT + (size_t)(bn + wave * 32 + (lane >> 3)) * K + (lane & 7) * 8;
  u16* Asb = As + wave * 32 * BK;
  u16* Bsb = Bs + wave * 32 * BK;

  for (int k0 = 0; k0 < K; k0 += BK) {
#pragma unroll
    for (int c = 0; c < 4; ++c) {
      GLD_LDS16(Ag + (size_t)c * 8 * K + k0, Asb + c * 8 * BK);
      GLD_LDS16(Bg + (size_t)c * 8 * K + k0, Bsb + c * 8 * BK);
    }
    __syncthreads();
#pragma unroll
    for (int kk = 0; kk < 2; ++kk) {
      bf16x8 af[4], bfv[4];
#pragma unroll
      for (int m = 0; m < 4; ++m)
        af[m] = *(const bf16x8*)&As[(wr + m * 16 + r) * BK + kk * 32 + kg * 8];
#pragma unroll
      for (int n = 0; n < 4; ++n)
        bfv[n] = *(const bf16x8*)&Bs[(wc + n * 16 + r) * BK + kk * 32 + kg * 8];
#pragma unroll
      for (int m = 0; m < 4; ++m)
#pragma unroll
        for (int n = 0; n < 4; ++n)
          acc[m][n] = __builtin_amdgcn_mfma_f32_16x16x32_bf16(af[m], bfv[n], acc[m][n], 0, 0, 0);
    }
    __syncthreads();
  }

#pragma unroll
  for (int m = 0; m < 4; ++m)
#pragma unroll
    for (int n = 0; n < 4; ++n) {
      if constexpr (OMODE == 2) {
        int row0 = bm + wr + m * 16 + kg * 4;
        int col = bn + wc + n * 16 + r;
        int bb = row0 >> 11, s = row0 & 2047;
        int hh = col >> 6, dd = col & 63;
        u16x4 pk;
#pragma unroll
        for (int i = 0; i < 4; ++i) pk[i] = f2b(acc[m][n][i] * scale);
        *(u16x4*)&((u16*)Cp)[((size_t)(bb * 16 + hh) * 64 + dd) * 2048 + s] = pk;
      } else {
#pragma unroll
        for (int i = 0; i < 4; ++i) {
          int row = bm + wr + m * 16 + kg * 4 + i;
          int col = bn + wc + n * 16 + r;
          if constexpr (OMODE == 1)
            ((float*)Cp)[(size_t)row * N + col] = acc[m][n][i] * scale;
          else
            ((u16*)Cp)[(size_t)row * N + col] = f2b(acc[m][n][i] * scale);
        }
      }
    }
}

// ---------------- flash attention: per (head, batch, qtile) ----------------
// Swapped QK^T: sv = mfma(K_frag, Q_frag) -> lane holds 16 scores of ONE
// q-row (q = r): softmax reduce = in-lane tree + shfl_xor(16,32). m/l scalar.
// V pre-transposed in global ([b][h][d][s]) so BOTH K and V stage via
// global_load_lds (no LDS scatter). All tiles 16B-chunk XOR-swizzled.
__global__ __launch_bounds__(256) void flash_attn(
    const u16* __restrict__ Q, const u16* __restrict__ Km, const u16* __restrict__ VtG,
    const float* __restrict__ bias, u16* __restrict__ ctx) {
  const int S = 2048, H = 1024;
  __shared__ __align__(16) u16 Ks[2][64 * 64];   // [buf][key][d] (swizzled)
  __shared__ __align__(16) u16 Vs[2][64 * 64];   // [buf][d][kv]  (swizzled)
  __shared__ __align__(16) u16 Ps[4][16 * 64];   // [wave][q][key](swizzled)
  int tid = threadIdx.x;
  int wave = tid >> 6, lane = tid & 63;
  int r = lane & 15, kg = lane >> 4;
  int h = blockIdx.x, b = blockIdx.y, qt = blockIdx.z;

  const u16* Qb = Q + (size_t)(b * S + qt * 64 + wave * 16 + r) * H + h * 64 + kg * 8;
  bf16x8 qa[2];
  qa[0] = *(const bf16x8*)(Qb);
  qa[1] = *(const bf16x8*)(Qb + 32);

  int lhi = lane >> 3, llo = lane & 7;
  int ksch = llo ^ lhi;  // pre-swizzled source chunk for DMA staging
  const u16* KgB = Km + (size_t)b * S * H + h * 64;
  const u16* VgB = VtG + ((size_t)(b * 16 + h) * 64) * 2048;  // rows d, stride S
  const float* biasB = bias + (size_t)b * S;

  float m_i = -1e30f, l_i = 0.f;
  f32x4 acc[4] = {};

  u16* Pw = &Ps[wave][0];

  auto issueKV = [&](int kv0, int bi) {
#pragma unroll
    for (int c = 0; c < 2; ++c) {
      GLD_LDS16(KgB + (size_t)(kv0 + wave * 16 + c * 8 + lhi) * H + ksch * 8,
                &Ks[bi][wave * 16 * 64 + c * 8 * 64]);
      GLD_LDS16(VgB + (size_t)(wave * 16 + c * 8 + lhi) * 2048 + kv0 + ksch * 8,
                &Vs[bi][wave * 16 * 64 + c * 8 * 64]);
    }
  };
  auto issueB = [&](int kv0, f32x4* bv) {
#pragma unroll
    for (int n = 0; n < 4; ++n)
      bv[n] = *(const f32x4*)(biasB + kv0 + n * 16 + (kg << 2));
  };

  auto compute = [&](const u16* KsB, const u16* VsB, const f32x4* bv) {
    // QK^T swapped: sv[n][i] = S^T[key = n*16+kg*4+i][q = r]
    f32x4 sv[4] = {};
    __builtin_amdgcn_s_setprio(1);
#pragma unroll
    for (int kk = 0; kk < 2; ++kk)
#pragma unroll
      for (int n = 0; n < 4; ++n) {
        bf16x8 kb = *(const bf16x8*)&KsB[(n * 16 + r) * 64 +
                                         ((((kk << 2) + kg) ^ (r & 7)) << 3)];
        sv[n] = __builtin_amdgcn_mfma_f32_16x16x32_bf16(kb, qa[kk], sv[n], 0, 0, 0);
      }
    __builtin_amdgcn_s_setprio(0);

    f32x4 s4[4];
#pragma unroll
    for (int n = 0; n < 4; ++n) s4[n] = sv[n] + bv[n];
    float m0 = fmaxf(fmaxf(s4[0][0], s4[0][1]), fmaxf(s4[0][2], s4[0][3]));
    float m1 = fmaxf(fmaxf(s4[1][0], s4[1][1]), fmaxf(s4[1][2], s4[1][3]));
    float m2 = fmaxf(fmaxf(s4[2][0], s4[2][1]), fmaxf(s4[2][2], s4[2][3]));
    float m3 = fmaxf(fmaxf(s4[3][0], s4[3][1]), fmaxf(s4[3][2], s4[3][3]));
    float mx = fmaxf(fmaxf(m0, m1), fmaxf(m2, m3));
    mx = fmaxf(mx, __shfl_xor(mx, 16));
    mx = fmaxf(mx, __shfl_xor(mx, 32));
    float sc = 1.f;
    if (mx > m_i + 8.f) { sc = __expf(m_i - mx); l_i *= sc; m_i = mx; }
    if (__any(sc != 1.f)) {
#pragma unroll
      for (int i = 0; i < 4; ++i) {
        float sci = __shfl(sc, (lane & 48) | ((kg << 2) + i));
#pragma unroll
        for (int n = 0; n < 4; ++n) acc[n][i] *= sci;
      }
    }
    float rs = 0.f;
    bf16x4 pk[4];
#pragma unroll
    for (int n = 0; n < 4; ++n)
#pragma unroll
      for (int i = 0; i < 4; ++i) {
        float e = __expf(s4[n][i] - m_i);
        rs += e;
        pk[n][i] = (__bf16)e;
      }
    rs += __shfl_xor(rs, 16);
    rs += __shfl_xor(rs, 32);
    l_i += rs;
    // P[q = r][key]: per n, 4 contiguous u16 at col n*16+kg*4 (swizzled chunk)
#pragma unroll
    for (int n = 0; n < 4; ++n)
      *(bf16x4*)&Pw[r * 64 + ((((2 * n + (kg >> 1)) ^ (r & 7)) << 3) | ((kg & 1) << 2))] =
          pk[n];

    // PV: acc[q = kg*4+i][d = n*16+r] += P[q][k] V^T[d][k]
    __builtin_amdgcn_s_setprio(1);
#pragma unroll
    for (int kk = 0; kk < 2; ++kk) {
      bf16x8 pa = *(const bf16x8*)&Pw[r * 64 + ((((kk << 2) + kg) ^ (r & 7)) << 3)];
#pragma unroll
      for (int n = 0; n < 4; ++n) {
        bf16x8 vb = *(const bf16x8*)&VsB[(n * 16 + r) * 64 +
                                         ((((kk << 2) + kg) ^ (r & 7)) << 3)];
        acc[n] = __builtin_amdgcn_mfma_f32_16x16x32_bf16(pa, vb, acc[n], 0, 0, 0);
      }
    }
    __builtin_amdgcn_s_setprio(0);
  };

  f32x4 bp[4], bn2[4];

  issueKV(0, 0); issueB(0, bp);
  __syncthreads();

  for (int t2 = 0; t2 < 16; ++t2) {
    int kv1 = (t2 * 2 + 1) * 64;
    int kv2 = ((t2 * 2 + 2) & 31) * 64;  // wraps at end (harmless refetch)
    issueKV(kv1, 1); issueB(kv1, bn2);
    compute(Ks[0], Vs[0], bp);
    __syncthreads();
    issueKV(kv2, 0); issueB(kv2, bp);
    compute(Ks[1], Vs[1], bn2);
    __syncthreads();
  }

#pragma unroll
  for (int i = 0; i < 4; ++i) {
    float li = __shfl(l_i, (lane & 48) | ((kg << 2) + i));
    float inv = 1.0f / li;
    size_t row = (size_t)(b * S + qt * 64 + wave * 16 + (kg << 2) + i);
#pragma unroll
    for (int n = 0; n < 4; ++n)
      ctx[row * H + h * 64 + n * 16 + r] = f2b(acc[n][i] * inv);
  }
}

extern "C" void kernel_launch(void* const* d_in, const int* in_sizes, int n_in,
                              void* d_out, int out_size, void* d_ws, size_t ws_size,
                              hipStream_t stream) {
  const float* x    = (const float*)d_in[0];
  const float* y    = (const float*)d_in[1];
  const float* bias = (const float*)d_in[2];
  const float* wq   = (const float*)d_in[3];
  const float* wk   = (const float*)d_in[4];
  const float* wv   = (const float*)d_in[5];
  const float* wo   = (const float*)d_in[6];
  float* out = (float*)d_out;  // reference output dtype is float32

  u16* ws = (u16*)d_ws;
  const size_t WELEM = 1024 * 1024;          // 2MB each (bf16)
  const size_t MELEM = (size_t)4096 * 1024;  // 8MB each (bf16)
  u16* wqT = ws;
  u16* wkT = wqT + WELEM;
  u16* wvT = wkT + WELEM;
  u16* woT = wvT + WELEM;
  u16* Qb  = woT + WELEM;
  u16* Kb  = Qb + MELEM;
  u16* Vb  = Kb + MELEM;   // holds V^T [b][h][d][s]
  u16* xb  = Vb + MELEM;   // x in bf16
  u16* yb  = xb + MELEM;   // y in bf16
  u16* Cb  = Qb;  // reuse: each flash block reads exactly the Q region it writes

  dim3 blk(256);
  transpose4<<<dim3(16, 16, 4), blk, 0, stream>>>(wq, wk, wv, wo, wqT, wkT, wvT, woT);
  cvt2bf16<<<dim3(2048, 2), blk, 0, stream>>>(x, y, xb, yb);
  gemm_bt<0><<<dim3(32, 8), blk, 0, stream>>>(xb, wqT, Qb, 0.125f);
  gemm_bt<0><<<dim3(32, 8), blk, 0, stream>>>(yb, wkT, Kb, 1.0f);
  gemm_bt<2><<<dim3(32, 8), blk, 0, stream>>>(yb, wvT, Vb, 1.0f);
  // (h,b) fastest -> same-(h,b) q-tiles share an XCD's L2
  flash_attn<<<dim3(16, 2, 32), blk, 0, stream>>>(Qb, Kb, Vb, bias, Cb);
  gemm_bt<1><<<dim3(32, 8), blk, 0, stream>>>(Cb, woT, out, 1.0f);
}

// Round 6
// 170.996 us; speedup vs baseline: 2.0580x; 1.1085x over previous
//
#include <hip/hip_runtime.h>

using u16 = unsigned short;
using u32 = unsigned int;

typedef __bf16 bf16x8 __attribute__((ext_vector_type(8)));
typedef __bf16 bf16x4 __attribute__((ext_vector_type(4)));
typedef float f32x4 __attribute__((ext_vector_type(4)));
typedef u16 u16x4 __attribute__((ext_vector_type(4)));

#define GLD_LDS16(gp, lp)                                                                 \
  __builtin_amdgcn_global_load_lds((const __attribute__((address_space(1))) void*)(gp),   \
                                   (__attribute__((address_space(3))) void*)(lp), 16, 0, 0)

__device__ __forceinline__ u16 f2b(float f) {
  union { float f; u32 u; } v; v.f = f;
  return (u16)((v.u + 0x7fffu + ((v.u >> 16) & 1u)) >> 16);
}

// ---------------- transpose+cast four 1024x1024 f32 weights -> bf16 W^T ----------------
__global__ __launch_bounds__(256) void transpose4(
    const float* __restrict__ w0, const float* __restrict__ w1,
    const float* __restrict__ w2, const float* __restrict__ w3,
    u16* __restrict__ o0, u16* __restrict__ o1,
    u16* __restrict__ o2, u16* __restrict__ o3) {
  const float* src; u16* dst;
  switch (blockIdx.z) {
    case 0: src = w0; dst = o0; break;
    case 1: src = w1; dst = o1; break;
    case 2: src = w2; dst = o2; break;
    default: src = w3; dst = o3; break;
  }
  __shared__ float tile[64][65];
  int bx = blockIdx.x * 64, by = blockIdx.y * 64;
  int tx = threadIdx.x & 63, ty = threadIdx.x >> 6;
  for (int r = ty; r < 64; r += 4)
    tile[r][tx] = src[(size_t)(by + r) * 1024 + bx + tx];
  __syncthreads();
  for (int r = ty; r < 64; r += 4)
    dst[(size_t)(bx + r) * 1024 + by + tx] = f2b(tile[tx][r]);
}

// ---------------- elementwise f32 -> bf16 for x and y (one launch) ----------------
__global__ __launch_bounds__(256) void cvt2bf16(
    const float* __restrict__ a, const float* __restrict__ b,
    u16* __restrict__ oa, u16* __restrict__ ob) {
  const float* src = blockIdx.y ? b : a;
  u16* dst = blockIdx.y ? ob : oa;
  size_t i = ((size_t)blockIdx.x * 256 + threadIdx.x) * 8;
  float4 f0 = *(const float4*)(src + i);
  float4 f1 = *(const float4*)(src + i + 4);
  bf16x8 v;
  v[0] = (__bf16)f0.x; v[1] = (__bf16)f0.y; v[2] = (__bf16)f0.z; v[3] = (__bf16)f0.w;
  v[4] = (__bf16)f1.x; v[5] = (__bf16)f1.y; v[6] = (__bf16)f1.z; v[7] = (__bf16)f1.w;
  *(bf16x8*)(dst + i) = v;
}

#define BM 128
#define BN 128
#define BK 64

// ------- fused QKV GEMM: region = blockIdx.y>>3 (0=Q,1=K,2=V); 768 blocks = 3/CU -------
__global__ __launch_bounds__(256) void gemm_qkv(
    const u16* __restrict__ xb, const u16* __restrict__ yb, const u16* __restrict__ wT,
    u16* __restrict__ Qb, u16* __restrict__ Kb, u16* __restrict__ Vb) {
  __shared__ __align__(16) u16 As[BM * BK];
  __shared__ __align__(16) u16 Bs[BN * BK];
  const int K = 1024;
  int region = blockIdx.y >> 3;
  const u16* A = (region == 0) ? xb : yb;
  const u16* BT = wT + (size_t)region * 1024 * 1024;
  float scale = (region == 0) ? 0.125f : 1.0f;
  int tid = threadIdx.x;
  int wave = tid >> 6, lane = tid & 63;
  int r = lane & 15, kg = lane >> 4;
  int bm = blockIdx.x * BM, bn = (blockIdx.y & 7) * BN;
  int wr = (wave >> 1) * 64, wc = (wave & 1) * 64;
  f32x4 acc[4][4] = {};

  const u16* Ag = A + (size_t)(bm + wave * 32 + (lane >> 3)) * K + (lane & 7) * 8;
  const u16* Bg = BT + (size_t)(bn + wave * 32 + (lane >> 3)) * K + (lane & 7) * 8;
  u16* Asb = As + wave * 32 * BK;
  u16* Bsb = Bs + wave * 32 * BK;

  for (int k0 = 0; k0 < K; k0 += BK) {
#pragma unroll
    for (int c = 0; c < 4; ++c) {
      GLD_LDS16(Ag + (size_t)c * 8 * K + k0, Asb + c * 8 * BK);
      GLD_LDS16(Bg + (size_t)c * 8 * K + k0, Bsb + c * 8 * BK);
    }
    __syncthreads();
#pragma unroll
    for (int kk = 0; kk < 2; ++kk) {
      bf16x8 af[4], bfv[4];
#pragma unroll
      for (int m = 0; m < 4; ++m)
        af[m] = *(const bf16x8*)&As[(wr + m * 16 + r) * BK + kk * 32 + kg * 8];
#pragma unroll
      for (int n = 0; n < 4; ++n)
        bfv[n] = *(const bf16x8*)&Bs[(wc + n * 16 + r) * BK + kk * 32 + kg * 8];
#pragma unroll
      for (int m = 0; m < 4; ++m)
#pragma unroll
        for (int n = 0; n < 4; ++n)
          acc[m][n] = __builtin_amdgcn_mfma_f32_16x16x32_bf16(af[m], bfv[n], acc[m][n], 0, 0, 0);
    }
    __syncthreads();
  }

  if (region == 2) {
    // V^T per-head: [b][h][d][s], b=row>>11, s=row&2047, h=col>>6, d=col&63
#pragma unroll
    for (int m = 0; m < 4; ++m)
#pragma unroll
      for (int n = 0; n < 4; ++n) {
        int row0 = bm + wr + m * 16 + kg * 4;
        int col = bn + wc + n * 16 + r;
        int bb = row0 >> 11, s = row0 & 2047;
        int hh = col >> 6, dd = col & 63;
        u16x4 pk;
#pragma unroll
        for (int i = 0; i < 4; ++i) pk[i] = f2b(acc[m][n][i]);
        *(u16x4*)&Vb[((size_t)(bb * 16 + hh) * 64 + dd) * 2048 + s] = pk;
      }
  } else {
    u16* dst = (region == 0) ? Qb : Kb;
#pragma unroll
    for (int m = 0; m < 4; ++m)
#pragma unroll
      for (int n = 0; n < 4; ++n)
#pragma unroll
        for (int i = 0; i < 4; ++i) {
          int row = bm + wr + m * 16 + kg * 4 + i;
          int col = bn + wc + n * 16 + r;
          dst[(size_t)row * 1024 + col] = f2b(acc[m][n][i] * scale);
        }
  }
}

// ------- WO GEMM: C[4096][1024] f32 = A[4096][1024](bf16) * W, BT = W^T -------
__global__ __launch_bounds__(256) void gemm_bt(
    const u16* __restrict__ A, const u16* __restrict__ BT, float* __restrict__ Cp,
    float scale) {
  __shared__ __align__(16) u16 As[BM * BK];
  __shared__ __align__(16) u16 Bs[BN * BK];
  const int K = 1024, N = 1024;
  int tid = threadIdx.x;
  int wave = tid >> 6, lane = tid & 63;
  int r = lane & 15, kg = lane >> 4;
  int bm = blockIdx.x * BM, bn = blockIdx.y * BN;
  int wr = (wave >> 1) * 64, wc = (wave & 1) * 64;
  f32x4 acc[4][4] = {};

  const u16* Ag = A + (size_t)(bm + wave * 32 + (lane >> 3)) * K + (lane & 7) * 8;
  const u16* Bg = BT + (size_t)(bn + wave * 32 + (lane >> 3)) * K + (lane & 7) * 8;
  u16* Asb = As + wave * 32 * BK;
  u16* Bsb = Bs + wave * 32 * BK;

  for (int k0 = 0; k0 < K; k0 += BK) {
#pragma unroll
    for (int c = 0; c < 4; ++c) {
      GLD_LDS16(Ag + (size_t)c * 8 * K + k0, Asb + c * 8 * BK);
      GLD_LDS16(Bg + (size_t)c * 8 * K + k0, Bsb + c * 8 * BK);
    }
    __syncthreads();
#pragma unroll
    for (int kk = 0; kk < 2; ++kk) {
      bf16x8 af[4], bfv[4];
#pragma unroll
      for (int m = 0; m < 4; ++m)
        af[m] = *(const bf16x8*)&As[(wr + m * 16 + r) * BK + kk * 32 + kg * 8];
#pragma unroll
      for (int n = 0; n < 4; ++n)
        bfv[n] = *(const bf16x8*)&Bs[(wc + n * 16 + r) * BK + kk * 32 + kg * 8];
#pragma unroll
      for (int m = 0; m < 4; ++m)
#pragma unroll
        for (int n = 0; n < 4; ++n)
          acc[m][n] = __builtin_amdgcn_mfma_f32_16x16x32_bf16(af[m], bfv[n], acc[m][n], 0, 0, 0);
    }
    __syncthreads();
  }

#pragma unroll
  for (int m = 0; m < 4; ++m)
#pragma unroll
    for (int n = 0; n < 4; ++n)
#pragma unroll
      for (int i = 0; i < 4; ++i) {
        int row = bm + wr + m * 16 + kg * 4 + i;
        int col = bn + wc + n * 16 + r;
        Cp[(size_t)row * N + col] = acc[m][n][i] * scale;
      }
}

// ---------------- flash attention: per (head, batch, qtile) ----------------
// R4-proven version (P through LDS; shfl_xor reductions). Swapped QK^T:
// sv = mfma(K_frag, Q_frag) -> lane holds 16 scores of ONE q-row (q = r).
// V pre-transposed in global ([b][h][d][s]) so BOTH K and V stage via
// global_load_lds (no LDS scatter). All tiles 16B-chunk XOR-swizzled.
__global__ __launch_bounds__(256) void flash_attn(
    const u16* __restrict__ Q, const u16* __restrict__ Km, const u16* __restrict__ VtG,
    const float* __restrict__ bias, u16* __restrict__ ctx) {
  const int S = 2048, H = 1024;
  __shared__ __align__(16) u16 Ks[2][64 * 64];   // [buf][key][d] (swizzled)
  __shared__ __align__(16) u16 Vs[2][64 * 64];   // [buf][d][kv]  (swizzled)
  __shared__ __align__(16) u16 Ps[4][16 * 64];   // [wave][q][key](swizzled)
  int tid = threadIdx.x;
  int wave = tid >> 6, lane = tid & 63;
  int r = lane & 15, kg = lane >> 4;
  int h = blockIdx.x, b = blockIdx.y, qt = blockIdx.z;

  const u16* Qb = Q + (size_t)(b * S + qt * 64 + wave * 16 + r) * H + h * 64 + kg * 8;
  bf16x8 qa[2];
  qa[0] = *(const bf16x8*)(Qb);
  qa[1] = *(const bf16x8*)(Qb + 32);

  int lhi = lane >> 3, llo = lane & 7;
  int ksch = llo ^ lhi;  // pre-swizzled source chunk for DMA staging
  const u16* KgB = Km + (size_t)b * S * H + h * 64;
  const u16* VgB = VtG + ((size_t)(b * 16 + h) * 64) * 2048;  // rows d, stride S
  const float* biasB = bias + (size_t)b * S;

  float m_i = -1e30f, l_i = 0.f;
  f32x4 acc[4] = {};

  u16* Pw = &Ps[wave][0];

  auto issueKV = [&](int kv0, int bi) {
#pragma unroll
    for (int c = 0; c < 2; ++c) {
      GLD_LDS16(KgB + (size_t)(kv0 + wave * 16 + c * 8 + lhi) * H + ksch * 8,
                &Ks[bi][wave * 16 * 64 + c * 8 * 64]);
      GLD_LDS16(VgB + (size_t)(wave * 16 + c * 8 + lhi) * 2048 + kv0 + ksch * 8,
                &Vs[bi][wave * 16 * 64 + c * 8 * 64]);
    }
  };
  auto issueB = [&](int kv0, f32x4* bv) {
#pragma unroll
    for (int n = 0; n < 4; ++n)
      bv[n] = *(const f32x4*)(biasB + kv0 + n * 16 + (kg << 2));
  };

  auto compute = [&](const u16* KsB, const u16* VsB, const f32x4* bv) {
    // QK^T swapped: sv[n][i] = S^T[key = n*16+kg*4+i][q = r]
    f32x4 sv[4] = {};
    __builtin_amdgcn_s_setprio(1);
#pragma unroll
    for (int kk = 0; kk < 2; ++kk)
#pragma unroll
      for (int n = 0; n < 4; ++n) {
        bf16x8 kb = *(const bf16x8*)&KsB[(n * 16 + r) * 64 +
                                         ((((kk << 2) + kg) ^ (r & 7)) << 3)];
        sv[n] = __builtin_amdgcn_mfma_f32_16x16x32_bf16(kb, qa[kk], sv[n], 0, 0, 0);
      }
    __builtin_amdgcn_s_setprio(0);

    f32x4 s4[4];
#pragma unroll
    for (int n = 0; n < 4; ++n) s4[n] = sv[n] + bv[n];
    float m0 = fmaxf(fmaxf(s4[0][0], s4[0][1]), fmaxf(s4[0][2], s4[0][3]));
    float m1 = fmaxf(fmaxf(s4[1][0], s4[1][1]), fmaxf(s4[1][2], s4[1][3]));
    float m2 = fmaxf(fmaxf(s4[2][0], s4[2][1]), fmaxf(s4[2][2], s4[2][3]));
    float m3 = fmaxf(fmaxf(s4[3][0], s4[3][1]), fmaxf(s4[3][2], s4[3][3]));
    float mx = fmaxf(fmaxf(m0, m1), fmaxf(m2, m3));
    mx = fmaxf(mx, __shfl_xor(mx, 16));
    mx = fmaxf(mx, __shfl_xor(mx, 32));
    float sc = 1.f;
    if (mx > m_i + 8.f) { sc = __expf(m_i - mx); l_i *= sc; m_i = mx; }
    if (__any(sc != 1.f)) {
#pragma unroll
      for (int i = 0; i < 4; ++i) {
        float sci = __shfl(sc, (lane & 48) | ((kg << 2) + i));
#pragma unroll
        for (int n = 0; n < 4; ++n) acc[n][i] *= sci;
      }
    }
    float rs = 0.f;
    bf16x4 pk[4];
#pragma unroll
    for (int n = 0; n < 4; ++n)
#pragma unroll
      for (int i = 0; i < 4; ++i) {
        float e = __expf(s4[n][i] - m_i);
        rs += e;
        pk[n][i] = (__bf16)e;
      }
    rs += __shfl_xor(rs, 16);
    rs += __shfl_xor(rs, 32);
    l_i += rs;
    // P[q = r][key]: per n, 4 contiguous u16 at col n*16+kg*4 (swizzled chunk)
#pragma unroll
    for (int n = 0; n < 4; ++n)
      *(bf16x4*)&Pw[r * 64 + ((((2 * n + (kg >> 1)) ^ (r & 7)) << 3) | ((kg & 1) << 2))] =
          pk[n];

    // PV: acc[q = kg*4+i][d = n*16+r] += P[q][k] V^T[d][k]
    __builtin_amdgcn_s_setprio(1);
#pragma unroll
    for (int kk = 0; kk < 2; ++kk) {
      bf16x8 pa = *(const bf16x8*)&Pw[r * 64 + ((((kk << 2) + kg) ^ (r & 7)) << 3)];
#pragma unroll
      for (int n = 0; n < 4; ++n) {
        bf16x8 vb = *(const bf16x8*)&VsB[(n * 16 + r) * 64 +
                                         ((((kk << 2) + kg) ^ (r & 7)) << 3)];
        acc[n] = __builtin_amdgcn_mfma_f32_16x16x32_bf16(pa, vb, acc[n], 0, 0, 0);
      }
    }
    __builtin_amdgcn_s_setprio(0);
  };

  f32x4 bp[4], bn2[4];

  issueKV(0, 0); issueB(0, bp);
  __syncthreads();

  for (int t2 = 0; t2 < 16; ++t2) {
    int kv1 = (t2 * 2 + 1) * 64;
    int kv2 = ((t2 * 2 + 2) & 31) * 64;  // wraps at end (harmless refetch)
    issueKV(kv1, 1); issueB(kv1, bn2);
    compute(Ks[0], Vs[0], bp);
    __syncthreads();
    issueKV(kv2, 0); issueB(kv2, bp);
    compute(Ks[1], Vs[1], bn2);
    __syncthreads();
  }

#pragma unroll
  for (int i = 0; i < 4; ++i) {
    float li = __shfl(l_i, (lane & 48) | ((kg << 2) + i));
    float inv = 1.0f / li;
    size_t row = (size_t)(b * S + qt * 64 + wave * 16 + (kg << 2) + i);
#pragma unroll
    for (int n = 0; n < 4; ++n)
      ctx[row * H + h * 64 + n * 16 + r] = f2b(acc[n][i] * inv);
  }
}

extern "C" void kernel_launch(void* const* d_in, const int* in_sizes, int n_in,
                              void* d_out, int out_size, void* d_ws, size_t ws_size,
                              hipStream_t stream) {
  const float* x    = (const float*)d_in[0];
  const float* y    = (const float*)d_in[1];
  const float* bias = (const float*)d_in[2];
  const float* wq   = (const float*)d_in[3];
  const float* wk   = (const float*)d_in[4];
  const float* wv   = (const float*)d_in[5];
  const float* wo   = (const float*)d_in[6];
  float* out = (float*)d_out;  // reference output dtype is float32

  u16* ws = (u16*)d_ws;
  const size_t WELEM = 1024 * 1024;          // 2MB each (bf16)
  const size_t MELEM = (size_t)4096 * 1024;  // 8MB each (bf16)
  u16* wqT = ws;                 // wqT|wkT|wvT contiguous (gemm_qkv indexes by region)
  u16* wkT = wqT + WELEM;
  u16* wvT = wkT + WELEM;
  u16* woT = wvT + WELEM;
  u16* Qb  = woT + WELEM;
  u16* Kb  = Qb + MELEM;
  u16* Vb  = Kb + MELEM;   // holds V^T [b][h][d][s]
  u16* xb  = Vb + MELEM;   // x in bf16
  u16* yb  = xb + MELEM;   // y in bf16
  u16* Cb  = Qb;  // reuse: each flash block reads exactly the Q region it writes

  dim3 blk(256);
  transpose4<<<dim3(16, 16, 4), blk, 0, stream>>>(wq, wk, wv, wo, wqT, wkT, wvT, woT);
  cvt2bf16<<<dim3(2048, 2), blk, 0, stream>>>(x, y, xb, yb);
  gemm_qkv<<<dim3(32, 24), blk, 0, stream>>>(xb, yb, wqT, Qb, Kb, Vb);
  // (h,b) fastest -> same-(h,b) q-tiles share an XCD's L2
  flash_attn<<<dim3(16, 2, 32), blk, 0, stream>>>(Qb, Kb, Vb, bias, Cb);
  gemm_bt<<<dim3(32, 8), blk, 0, stream>>>(Cb, woT, out, 1.0f);
}